// Round 1
// baseline (6064.629 us; speedup 1.0000x reference)
//
#include <hip/hip_runtime.h>
#include <math.h>

#define NODES 100000
#define EDGES 1600000
#define HF 128
#define NC 20

__global__ void degree_kernel(const int* __restrict__ dst, float* __restrict__ cnt, int E) {
    int e = blockIdx.x * blockDim.x + threadIdx.x;
    if (e < E) unsafeAtomicAdd(&cnt[dst[e]], 1.0f);
}

__global__ void inv_kernel(float* __restrict__ cnt, int n) {
    int i = blockIdx.x * blockDim.x + threadIdx.x;
    if (i < n) cnt[i] = 1.0f / fmaxf(cnt[i], 1.0f);
}

// 32 lanes per edge, float4 per lane: gather x[src] row, atomic-add into agg[dst] row.
__global__ void scatter_kernel(const float* __restrict__ x, const int* __restrict__ src,
                               const int* __restrict__ dst, float* __restrict__ agg, int E) {
    int tid = blockIdx.x * blockDim.x + threadIdx.x;
    int e = tid >> 5;
    if (e >= E) return;
    int c = (tid & 31) << 2;
    int s = src[e], d = dst[e];
    const float4 v = *(const float4*)(x + (size_t)s * HF + c);
    float* dp = agg + (size_t)d * HF + c;
    unsafeAtomicAdd(dp + 0, v.x);
    unsafeAtomicAdd(dp + 1, v.y);
    unsafeAtomicAdd(dp + 2, v.z);
    unsafeAtomicAdd(dp + 3, v.w);
}

// out[i][j] = act( bias[j] + sum_k (A1[i][k]*inv[i]) * W1[j][k]  (+ sum_k A2[i][k]*W2[j][k]) )
// blockDim = 128 (thread = output column j), ROWS rows per block.
template<int ROWS, bool DUAL>
__global__ void linear_kernel(const float* __restrict__ A1, const float* __restrict__ inv,
                              const float* __restrict__ A2,
                              const float* __restrict__ W1, const float* __restrict__ W2,
                              const float* __restrict__ bias, float* __restrict__ out, int n) {
    __shared__ float sA1[ROWS * HF];
    __shared__ float sA2[ROWS * HF];
    int row0 = blockIdx.x * ROWS;

    for (int idx = threadIdx.x; idx < ROWS * HF; idx += blockDim.x) {
        int r = idx >> 7, k = idx & (HF - 1);
        int i = row0 + r;
        float a1 = 0.f, a2 = 0.f;
        if (i < n) {
            a1 = A1[(size_t)i * HF + k];
            if (inv) a1 *= inv[i];
            if (DUAL) a2 = A2[(size_t)i * HF + k];
        }
        sA1[idx] = a1;
        if (DUAL) sA2[idx] = a2;
    }
    __syncthreads();

    int j = threadIdx.x;  // 0..127
    float acc[ROWS];
#pragma unroll
    for (int r = 0; r < ROWS; ++r) acc[r] = 0.f;

    const float4* W1v = (const float4*)(W1 + (size_t)j * HF);
    const float4* W2v = (const float4*)(W2 + (size_t)j * HF);

#pragma unroll 4
    for (int k4 = 0; k4 < HF / 4; ++k4) {
        float4 w1 = W1v[k4];
        float4 w2;
        if (DUAL) w2 = W2v[k4];
#pragma unroll
        for (int r = 0; r < ROWS; ++r) {
            float4 a1 = *(const float4*)(sA1 + r * HF + k4 * 4);  // broadcast read
            acc[r] = fmaf(a1.x, w1.x, fmaf(a1.y, w1.y, fmaf(a1.z, w1.z, fmaf(a1.w, w1.w, acc[r]))));
            if (DUAL) {
                float4 a2 = *(const float4*)(sA2 + r * HF + k4 * 4);
                acc[r] = fmaf(a2.x, w2.x, fmaf(a2.y, w2.y, fmaf(a2.z, w2.z, fmaf(a2.w, w2.w, acc[r]))));
            }
        }
    }

    float b = bias[j];
#pragma unroll
    for (int r = 0; r < ROWS; ++r) {
        int i = row0 + r;
        if (i < n) {
            float v = acc[r] + b;
            out[(size_t)i * HF + j] = fmaxf(v, 0.f);
        }
    }
}

// out[i][j] = sigmoid(bm2[j] + sum_k A[i][k]*W[j][k]), j < 20. 8 rows/block, 256 threads.
__global__ void head_kernel(const float* __restrict__ A, const float* __restrict__ W,
                            const float* __restrict__ bias, float* __restrict__ out, int n) {
    const int ROWS = 8;
    __shared__ float sA[ROWS * 129];
    __shared__ float sW[NC * 129];
    int row0 = blockIdx.x * ROWS;

    for (int idx = threadIdx.x; idx < NC * HF; idx += blockDim.x) {
        int j = idx >> 7, k = idx & (HF - 1);
        sW[j * 129 + k] = W[idx];
    }
    for (int idx = threadIdx.x; idx < ROWS * HF; idx += blockDim.x) {
        int r = idx >> 7, k = idx & (HF - 1);
        int i = row0 + r;
        sA[r * 129 + k] = (i < n) ? A[(size_t)i * HF + k] : 0.f;
    }
    __syncthreads();

    int t = threadIdx.x;
    if (t < ROWS * NC) {
        int r = t / NC, j = t - r * NC;
        int i = row0 + r;
        if (i < n) {
            float acc = bias[j];
#pragma unroll 8
            for (int k = 0; k < HF; ++k)
                acc = fmaf(sA[r * 129 + k], sW[j * 129 + k], acc);
            out[(size_t)i * NC + j] = 1.0f / (1.0f + expf(-acc));
        }
    }
}

extern "C" void kernel_launch(void* const* d_in, const int* in_sizes, int n_in,
                              void* d_out, int out_size, void* d_ws, size_t ws_size,
                              hipStream_t stream) {
    const float* x   = (const float*)d_in[0];
    const int*   ei  = (const int*)d_in[1];
    const float* W1l = (const float*)d_in[2];
    const float* b1  = (const float*)d_in[3];
    const float* W1r = (const float*)d_in[4];
    const float* W2l = (const float*)d_in[5];
    const float* b2  = (const float*)d_in[6];
    const float* W2r = (const float*)d_in[7];
    const float* Wm1 = (const float*)d_in[8];
    const float* bm1 = (const float*)d_in[9];
    const float* Wm2 = (const float*)d_in[10];
    const float* bm2 = (const float*)d_in[11];
    float* out = (float*)d_out;

    const int N = NODES, E = EDGES;
    const int* src = ei;
    const int* dst = ei + E;

    float* ws  = (float*)d_ws;
    float* inv = ws;                       // N floats (deg count, then 1/max(deg,1))
    float* agg = ws + N;                   // N*HF
    float* h1  = agg + (size_t)N * HF;     // N*HF
    float* h2  = h1 + (size_t)N * HF;      // N*HF
    float* h3  = agg;                      // reuse agg after layer 2

    // degree -> inverse
    hipMemsetAsync(inv, 0, (size_t)N * sizeof(float), stream);
    degree_kernel<<<(E + 255) / 256, 256, 0, stream>>>(dst, inv, E);
    inv_kernel<<<(N + 255) / 256, 256, 0, stream>>>(inv, N);

    // layer 1
    hipMemsetAsync(agg, 0, (size_t)N * HF * sizeof(float), stream);
    scatter_kernel<<<(E * 32 + 255) / 256, 256, 0, stream>>>(x, src, dst, agg, E);
    linear_kernel<8, true><<<(N + 7) / 8, 128, 0, stream>>>(agg, inv, x, W1l, W1r, b1, h1, N);

    // layer 2
    hipMemsetAsync(agg, 0, (size_t)N * HF * sizeof(float), stream);
    scatter_kernel<<<(E * 32 + 255) / 256, 256, 0, stream>>>(h1, src, dst, agg, E);
    linear_kernel<8, true><<<(N + 7) / 8, 128, 0, stream>>>(agg, inv, h1, W2l, W2r, b2, h2, N);

    // MLP hidden
    linear_kernel<8, false><<<(N + 7) / 8, 128, 0, stream>>>(h2, nullptr, nullptr, Wm1, nullptr, bm1, h3, N);

    // head + sigmoid
    head_kernel<<<(N + 7) / 8, 256, 0, stream>>>(h3, Wm2, bm2, out, N);
}

// Round 2
// 1327.960 us; speedup vs baseline: 4.5669x; 4.5669x over previous
//
#include <hip/hip_runtime.h>
#include <math.h>

#define NODES 100000
#define EDGES 1600000
#define HF 128
#define NC 20

// ---- edge sort by dst (counting sort), once per launch ----

__global__ void count_kernel(const int* __restrict__ dst, int* __restrict__ deg, int E) {
    int e = blockIdx.x * blockDim.x + threadIdx.x;
    if (e < E) atomicAdd(&deg[dst[e]], 1);
}

// single block, 1024 threads: exclusive scan of deg[0..n) -> off[0..n], cursor copy
__global__ void scan_kernel(const int* __restrict__ deg, int* __restrict__ off,
                            int* __restrict__ cursor, int n) {
    __shared__ int partial[1024];
    int t = threadIdx.x;
    const int CH = (n + 1023) / 1024;
    int base = t * CH;
    int sum = 0;
    for (int i = 0; i < CH; ++i) {
        int idx = base + i;
        if (idx < n) sum += deg[idx];
    }
    partial[t] = sum;
    __syncthreads();
    for (int s = 1; s < 1024; s <<= 1) {
        int v = 0;
        if (t >= s) v = partial[t - s];
        __syncthreads();
        if (t >= s) partial[t] += v;
        __syncthreads();
    }
    int run = (t == 0) ? 0 : partial[t - 1];
    for (int i = 0; i < CH; ++i) {
        int idx = base + i;
        if (idx < n) {
            off[idx] = run;
            cursor[idx] = run;
            run += deg[idx];
        }
    }
    if (t == 1023) off[n] = partial[1023];
}

__global__ void sort_kernel(const int* __restrict__ src, const int* __restrict__ dst,
                            int* __restrict__ cursor, int* __restrict__ ssrc, int E) {
    int e = blockIdx.x * blockDim.x + threadIdx.x;
    if (e < E) {
        int pos = atomicAdd(&cursor[dst[e]], 1);
        ssrc[pos] = src[e];
    }
}

// ---- mean-aggregate: 32 lanes per node, gather rows of x over the node's edge segment ----
__global__ void aggregate_kernel(const float* __restrict__ x, const int* __restrict__ ssrc,
                                 const int* __restrict__ off, float* __restrict__ agg, int n) {
    int tid = blockIdx.x * blockDim.x + threadIdx.x;
    int node = tid >> 5;
    if (node >= n) return;
    int c = (tid & 31) << 2;
    int s0 = off[node], s1 = off[node + 1];
    float4 acc = {0.f, 0.f, 0.f, 0.f};
    int e = s0;
    for (; e + 1 < s1; e += 2) {
        int sa = ssrc[e], sb = ssrc[e + 1];
        float4 va = *(const float4*)(x + (size_t)sa * HF + c);
        float4 vb = *(const float4*)(x + (size_t)sb * HF + c);
        acc.x += va.x + vb.x; acc.y += va.y + vb.y;
        acc.z += va.z + vb.z; acc.w += va.w + vb.w;
    }
    if (e < s1) {
        int sa = ssrc[e];
        float4 va = *(const float4*)(x + (size_t)sa * HF + c);
        acc.x += va.x; acc.y += va.y; acc.z += va.z; acc.w += va.w;
    }
    float invd = 1.0f / fmaxf((float)(s1 - s0), 1.0f);
    acc.x *= invd; acc.y *= invd; acc.z *= invd; acc.w *= invd;
    *(float4*)(agg + (size_t)node * HF + c) = acc;
}

// out[i][j] = relu( bias[j] + sum_k A1[i][k]*W1[j][k] (+ sum_k A2[i][k]*W2[j][k]) )
// In-place safe (out may alias A1/A2): rows are block-private and staged via LDS.
template<int ROWS, bool DUAL>
__global__ void linear_kernel(const float* __restrict__ A1, const float* __restrict__ A2,
                              const float* __restrict__ W1, const float* __restrict__ W2,
                              const float* __restrict__ bias, float* __restrict__ out, int n) {
    __shared__ float sA1[ROWS * HF];
    __shared__ float sA2[ROWS * HF];
    int row0 = blockIdx.x * ROWS;

    for (int idx = threadIdx.x; idx < ROWS * HF; idx += blockDim.x) {
        int r = idx >> 7, k = idx & (HF - 1);
        int i = row0 + r;
        float a1 = 0.f, a2 = 0.f;
        if (i < n) {
            a1 = A1[(size_t)i * HF + k];
            if (DUAL) a2 = A2[(size_t)i * HF + k];
        }
        sA1[idx] = a1;
        if (DUAL) sA2[idx] = a2;
    }
    __syncthreads();

    int j = threadIdx.x;  // 0..127
    float acc[ROWS];
#pragma unroll
    for (int r = 0; r < ROWS; ++r) acc[r] = 0.f;

    const float4* W1v = (const float4*)(W1 + (size_t)j * HF);
    const float4* W2v = (const float4*)(W2 + (size_t)j * HF);

#pragma unroll 4
    for (int k4 = 0; k4 < HF / 4; ++k4) {
        float4 w1 = W1v[k4];
        float4 w2;
        if (DUAL) w2 = W2v[k4];
#pragma unroll
        for (int r = 0; r < ROWS; ++r) {
            float4 a1 = *(const float4*)(sA1 + r * HF + k4 * 4);
            acc[r] = fmaf(a1.x, w1.x, fmaf(a1.y, w1.y, fmaf(a1.z, w1.z, fmaf(a1.w, w1.w, acc[r]))));
            if (DUAL) {
                float4 a2 = *(const float4*)(sA2 + r * HF + k4 * 4);
                acc[r] = fmaf(a2.x, w2.x, fmaf(a2.y, w2.y, fmaf(a2.z, w2.z, fmaf(a2.w, w2.w, acc[r]))));
            }
        }
    }

    float b = bias[j];
#pragma unroll
    for (int r = 0; r < ROWS; ++r) {
        int i = row0 + r;
        if (i < n) {
            float v = acc[r] + b;
            out[(size_t)i * HF + j] = fmaxf(v, 0.f);
        }
    }
}

// out[i][j] = sigmoid(bm2[j] + sum_k A[i][k]*W[j][k]), j < 20.
__global__ void head_kernel(const float* __restrict__ A, const float* __restrict__ W,
                            const float* __restrict__ bias, float* __restrict__ out, int n) {
    const int ROWS = 8;
    __shared__ float sA[ROWS * 129];
    __shared__ float sW[NC * 129];
    int row0 = blockIdx.x * ROWS;

    for (int idx = threadIdx.x; idx < NC * HF; idx += blockDim.x) {
        int j = idx >> 7, k = idx & (HF - 1);
        sW[j * 129 + k] = W[idx];
    }
    for (int idx = threadIdx.x; idx < ROWS * HF; idx += blockDim.x) {
        int r = idx >> 7, k = idx & (HF - 1);
        int i = row0 + r;
        sA[r * 129 + k] = (i < n) ? A[(size_t)i * HF + k] : 0.f;
    }
    __syncthreads();

    int t = threadIdx.x;
    if (t < ROWS * NC) {
        int r = t / NC, j = t - r * NC;
        int i = row0 + r;
        if (i < n) {
            float acc = bias[j];
#pragma unroll 8
            for (int k = 0; k < HF; ++k)
                acc = fmaf(sA[r * 129 + k], sW[j * 129 + k], acc);
            out[(size_t)i * NC + j] = 1.0f / (1.0f + expf(-acc));
        }
    }
}

extern "C" void kernel_launch(void* const* d_in, const int* in_sizes, int n_in,
                              void* d_out, int out_size, void* d_ws, size_t ws_size,
                              hipStream_t stream) {
    const float* x   = (const float*)d_in[0];
    const int*   ei  = (const int*)d_in[1];
    const float* W1l = (const float*)d_in[2];
    const float* b1  = (const float*)d_in[3];
    const float* W1r = (const float*)d_in[4];
    const float* W2l = (const float*)d_in[5];
    const float* b2  = (const float*)d_in[6];
    const float* W2r = (const float*)d_in[7];
    const float* Wm1 = (const float*)d_in[8];
    const float* bm1 = (const float*)d_in[9];
    const float* Wm2 = (const float*)d_in[10];
    const float* bm2 = (const float*)d_in[11];
    float* out = (float*)d_out;

    const int N = NODES, E = EDGES;
    const int* src = ei;
    const int* dst = ei + E;

    // workspace layout (all 4-byte elements)
    int*   deg    = (int*)d_ws;                 // N
    int*   off    = deg + N;                    // N+1
    int*   cursor = off + N + 1;                // N
    int*   ssrc   = cursor + N;                 // E
    float* bufA   = (float*)(ssrc + E);         // N*HF
    float* bufB   = bufA + (size_t)N * HF;      // N*HF

    // ---- sort edges by dst ----
    hipMemsetAsync(deg, 0, (size_t)N * sizeof(int), stream);
    count_kernel<<<(E + 255) / 256, 256, 0, stream>>>(dst, deg, E);
    scan_kernel<<<1, 1024, 0, stream>>>(deg, off, cursor, N);
    sort_kernel<<<(E + 255) / 256, 256, 0, stream>>>(src, dst, cursor, ssrc, E);

    const int aggBlocks = (N * 32 + 255) / 256;

    // ---- layer 1: mean-agg(x) -> bufA; relu(bufA@W1l^T + b1 + x@W1r^T) -> bufA ----
    aggregate_kernel<<<aggBlocks, 256, 0, stream>>>(x, ssrc, off, bufA, N);
    linear_kernel<8, true><<<(N + 7) / 8, 128, 0, stream>>>(bufA, x, W1l, W1r, b1, bufA, N);

    // ---- layer 2: mean-agg(h1=bufA) -> bufB; relu(...) -> bufB ----
    aggregate_kernel<<<aggBlocks, 256, 0, stream>>>(bufA, ssrc, off, bufB, N);
    linear_kernel<8, true><<<(N + 7) / 8, 128, 0, stream>>>(bufB, bufA, W2l, W2r, b2, bufB, N);

    // ---- MLP hidden (in-place) ----
    linear_kernel<8, false><<<(N + 7) / 8, 128, 0, stream>>>(bufB, nullptr, Wm1, nullptr, bm1, bufB, N);

    // ---- head + sigmoid ----
    head_kernel<<<(N + 7) / 8, 256, 0, stream>>>(bufB, Wm2, bm2, out, N);
}

// Round 3
// 1086.784 us; speedup vs baseline: 5.5803x; 1.2219x over previous
//
#include <hip/hip_runtime.h>
#include <math.h>

#define NODES 100000
#define EDGES 1600000
#define HF 128
#define NC 20
#define SCAN_CHUNK 1024

// ---- edge sort by dst (counting sort), once per launch ----

__global__ void count_kernel(const int* __restrict__ dst, int* __restrict__ deg, int E) {
    int e = blockIdx.x * blockDim.x + threadIdx.x;
    if (e < E) atomicAdd(&deg[dst[e]], 1);
}

// pass 1: per-block (1024-element chunk) reduction -> bsum[b]
__global__ void scan_part1(const int* __restrict__ deg, int* __restrict__ bsum, int n) {
    __shared__ int p[256];
    int t = threadIdx.x;
    int base = blockIdx.x * SCAN_CHUNK + t * 4;
    int s = 0;
#pragma unroll
    for (int i = 0; i < 4; ++i) {
        int idx = base + i;
        if (idx < n) s += deg[idx];
    }
    p[t] = s;
    __syncthreads();
    for (int st = 128; st > 0; st >>= 1) {
        if (t < st) p[t] += p[t + st];
        __syncthreads();
    }
    if (t == 0) bsum[blockIdx.x] = p[0];
}

// pass 2: per-block offset (sum of bsum[0..b)) + local exclusive scan -> off/cursor
__global__ void scan_part2(const int* __restrict__ deg, const int* __restrict__ bsum,
                           int* __restrict__ off, int* __restrict__ cursor, int n, int nb) {
    __shared__ int p[256];
    __shared__ int sboff;
    int t = threadIdx.x;
    int b = blockIdx.x;

    // block offset = sum of bsum[0..b)
    int s = 0;
    for (int i = t; i < b; i += 256) s += bsum[i];
    p[t] = s;
    __syncthreads();
    for (int st = 128; st > 0; st >>= 1) {
        if (t < st) p[t] += p[t + st];
        __syncthreads();
    }
    if (t == 0) sboff = p[0];
    __syncthreads();
    int boff = sboff;

    // local scan of this block's 1024 elements (4 per thread)
    int base = b * SCAN_CHUNK + t * 4;
    int d[4];
    int s4 = 0;
#pragma unroll
    for (int i = 0; i < 4; ++i) {
        int idx = base + i;
        d[i] = (idx < n) ? deg[idx] : 0;
        s4 += d[i];
    }
    __syncthreads();  // protect p reuse
    p[t] = s4;
    __syncthreads();
    for (int st = 1; st < 256; st <<= 1) {
        int v = (t >= st) ? p[t - st] : 0;
        __syncthreads();
        p[t] += v;
        __syncthreads();
    }
    int excl = boff + ((t == 0) ? 0 : p[t - 1]);
#pragma unroll
    for (int i = 0; i < 4; ++i) {
        int idx = base + i;
        if (idx < n) {
            off[idx] = excl;
            cursor[idx] = excl;
            excl += d[i];
        }
    }
    if (b == nb - 1 && t == 255) off[n] = boff + p[255];
}

__global__ void sort_kernel(const int* __restrict__ src, const int* __restrict__ dst,
                            int* __restrict__ cursor, int* __restrict__ ssrc, int E) {
    int e = blockIdx.x * blockDim.x + threadIdx.x;
    if (e < E) {
        int pos = atomicAdd(&cursor[dst[e]], 1);
        ssrc[pos] = src[e];
    }
}

// ---- mean-aggregate: 32 lanes per node, gather rows of x over the node's edge segment ----
__global__ void aggregate_kernel(const float* __restrict__ x, const int* __restrict__ ssrc,
                                 const int* __restrict__ off, float* __restrict__ agg, int n) {
    int tid = blockIdx.x * blockDim.x + threadIdx.x;
    int node = tid >> 5;
    if (node >= n) return;
    int c = (tid & 31) << 2;
    int s0 = off[node], s1 = off[node + 1];
    float4 acc = {0.f, 0.f, 0.f, 0.f};
    int e = s0;
    for (; e + 1 < s1; e += 2) {
        int sa = ssrc[e], sb = ssrc[e + 1];
        float4 va = *(const float4*)(x + (size_t)sa * HF + c);
        float4 vb = *(const float4*)(x + (size_t)sb * HF + c);
        acc.x += va.x + vb.x; acc.y += va.y + vb.y;
        acc.z += va.z + vb.z; acc.w += va.w + vb.w;
    }
    if (e < s1) {
        int sa = ssrc[e];
        float4 va = *(const float4*)(x + (size_t)sa * HF + c);
        acc.x += va.x; acc.y += va.y; acc.z += va.z; acc.w += va.w;
    }
    float invd = 1.0f / fmaxf((float)(s1 - s0), 1.0f);
    acc.x *= invd; acc.y *= invd; acc.z *= invd; acc.w *= invd;
    *(float4*)(agg + (size_t)node * HF + c) = acc;
}

// out[i][j] = relu( bias[j] + sum_k A1[i][k]*W1[j][k] (+ sum_k A2[i][k]*W2[j][k]) )
// In-place safe (out may alias A1/A2): rows are block-private and staged via LDS.
template<int ROWS, bool DUAL>
__global__ void linear_kernel(const float* __restrict__ A1, const float* __restrict__ A2,
                              const float* __restrict__ W1, const float* __restrict__ W2,
                              const float* __restrict__ bias, float* __restrict__ out, int n) {
    __shared__ float sA1[ROWS * HF];
    __shared__ float sA2[ROWS * HF];
    int row0 = blockIdx.x * ROWS;

    for (int idx = threadIdx.x; idx < ROWS * HF; idx += blockDim.x) {
        int r = idx >> 7, k = idx & (HF - 1);
        int i = row0 + r;
        float a1 = 0.f, a2 = 0.f;
        if (i < n) {
            a1 = A1[(size_t)i * HF + k];
            if (DUAL) a2 = A2[(size_t)i * HF + k];
        }
        sA1[idx] = a1;
        if (DUAL) sA2[idx] = a2;
    }
    __syncthreads();

    int j = threadIdx.x;  // 0..127
    float acc[ROWS];
#pragma unroll
    for (int r = 0; r < ROWS; ++r) acc[r] = 0.f;

    const float4* W1v = (const float4*)(W1 + (size_t)j * HF);
    const float4* W2v = (const float4*)(W2 + (size_t)j * HF);

#pragma unroll 4
    for (int k4 = 0; k4 < HF / 4; ++k4) {
        float4 w1 = W1v[k4];
        float4 w2;
        if (DUAL) w2 = W2v[k4];
#pragma unroll
        for (int r = 0; r < ROWS; ++r) {
            float4 a1 = *(const float4*)(sA1 + r * HF + k4 * 4);
            acc[r] = fmaf(a1.x, w1.x, fmaf(a1.y, w1.y, fmaf(a1.z, w1.z, fmaf(a1.w, w1.w, acc[r]))));
            if (DUAL) {
                float4 a2 = *(const float4*)(sA2 + r * HF + k4 * 4);
                acc[r] = fmaf(a2.x, w2.x, fmaf(a2.y, w2.y, fmaf(a2.z, w2.z, fmaf(a2.w, w2.w, acc[r]))));
            }
        }
    }

    float b = bias[j];
#pragma unroll
    for (int r = 0; r < ROWS; ++r) {
        int i = row0 + r;
        if (i < n) {
            float v = acc[r] + b;
            out[(size_t)i * HF + j] = fmaxf(v, 0.f);
        }
    }
}

// out[i][j] = sigmoid(bm2[j] + sum_k A[i][k]*W[j][k]), j < 20.
__global__ void head_kernel(const float* __restrict__ A, const float* __restrict__ W,
                            const float* __restrict__ bias, float* __restrict__ out, int n) {
    const int ROWS = 8;
    __shared__ float sA[ROWS * 129];
    __shared__ float sW[NC * 129];
    int row0 = blockIdx.x * ROWS;

    for (int idx = threadIdx.x; idx < NC * HF; idx += blockDim.x) {
        int j = idx >> 7, k = idx & (HF - 1);
        sW[j * 129 + k] = W[idx];
    }
    for (int idx = threadIdx.x; idx < ROWS * HF; idx += blockDim.x) {
        int r = idx >> 7, k = idx & (HF - 1);
        int i = row0 + r;
        sA[r * 129 + k] = (i < n) ? A[(size_t)i * HF + k] : 0.f;
    }
    __syncthreads();

    int t = threadIdx.x;
    if (t < ROWS * NC) {
        int r = t / NC, j = t - r * NC;
        int i = row0 + r;
        if (i < n) {
            float acc = bias[j];
#pragma unroll 8
            for (int k = 0; k < HF; ++k)
                acc = fmaf(sA[r * 129 + k], sW[j * 129 + k], acc);
            out[(size_t)i * NC + j] = 1.0f / (1.0f + expf(-acc));
        }
    }
}

extern "C" void kernel_launch(void* const* d_in, const int* in_sizes, int n_in,
                              void* d_out, int out_size, void* d_ws, size_t ws_size,
                              hipStream_t stream) {
    const float* x   = (const float*)d_in[0];
    const int*   ei  = (const int*)d_in[1];
    const float* W1l = (const float*)d_in[2];
    const float* b1  = (const float*)d_in[3];
    const float* W1r = (const float*)d_in[4];
    const float* W2l = (const float*)d_in[5];
    const float* b2  = (const float*)d_in[6];
    const float* W2r = (const float*)d_in[7];
    const float* Wm1 = (const float*)d_in[8];
    const float* bm1 = (const float*)d_in[9];
    const float* Wm2 = (const float*)d_in[10];
    const float* bm2 = (const float*)d_in[11];
    float* out = (float*)d_out;

    const int N = NODES, E = EDGES;
    const int* src = ei;
    const int* dst = ei + E;

    // workspace layout (all 4-byte elements)
    int*   deg    = (int*)d_ws;                 // N
    int*   off    = deg + N;                    // N+1
    int*   cursor = off + N + 1;                // N
    int*   bsum   = cursor + N;                 // NB
    int*   ssrc   = bsum + 256;                 // E
    float* bufA   = (float*)(ssrc + E);         // N*HF
    float* bufB   = bufA + (size_t)N * HF;      // N*HF

    const int NB = (N + SCAN_CHUNK - 1) / SCAN_CHUNK;

    // ---- sort edges by dst ----
    hipMemsetAsync(deg, 0, (size_t)N * sizeof(int), stream);
    count_kernel<<<(E + 255) / 256, 256, 0, stream>>>(dst, deg, E);
    scan_part1<<<NB, 256, 0, stream>>>(deg, bsum, N);
    scan_part2<<<NB, 256, 0, stream>>>(deg, bsum, off, cursor, N, NB);
    sort_kernel<<<(E + 255) / 256, 256, 0, stream>>>(src, dst, cursor, ssrc, E);

    const int aggBlocks = (N * 32 + 255) / 256;

    // ---- layer 1: mean-agg(x) -> bufA; relu(bufA@W1l^T + b1 + x@W1r^T) -> bufA ----
    aggregate_kernel<<<aggBlocks, 256, 0, stream>>>(x, ssrc, off, bufA, N);
    linear_kernel<8, true><<<(N + 7) / 8, 128, 0, stream>>>(bufA, x, W1l, W1r, b1, bufA, N);

    // ---- layer 2: mean-agg(h1=bufA) -> bufB; relu(...) -> bufB ----
    aggregate_kernel<<<aggBlocks, 256, 0, stream>>>(bufA, ssrc, off, bufB, N);
    linear_kernel<8, true><<<(N + 7) / 8, 128, 0, stream>>>(bufB, bufA, W2l, W2r, b2, bufB, N);

    // ---- MLP hidden (in-place) ----
    linear_kernel<8, false><<<(N + 7) / 8, 128, 0, stream>>>(bufB, nullptr, Wm1, nullptr, bm1, bufB, N);

    // ---- head + sigmoid ----
    head_kernel<<<(N + 7) / 8, 256, 0, stream>>>(bufB, Wm2, bm2, out, N);
}

// Round 4
// 631.897 us; speedup vs baseline: 9.5975x; 1.7199x over previous
//
#include <hip/hip_runtime.h>
#include <math.h>

#define NODES 100000
#define EDGES 1600000
#define HF 128
#define NC 20
#define SCAN_CHUNK 1024

typedef __attribute__((ext_vector_type(8))) short bf16x8;
typedef __attribute__((ext_vector_type(4))) float f32x4;

__device__ __forceinline__ ushort f2b(float f) {
    uint u = __float_as_uint(f);
    uint r = (u + 0x7FFFu + ((u >> 16) & 1u)) >> 16;
    return (ushort)r;
}
__device__ __forceinline__ float b2f(ushort h) { return __uint_as_float(((uint)h) << 16); }
__device__ __forceinline__ float4 unpk(uint2 v) {
    float4 r;
    r.x = __uint_as_float(v.x << 16);
    r.y = __uint_as_float(v.x & 0xFFFF0000u);
    r.z = __uint_as_float(v.y << 16);
    r.w = __uint_as_float(v.y & 0xFFFF0000u);
    return r;
}

// ---- edge sort by dst (counting sort) ----

__global__ void count_kernel(const int* __restrict__ dst, int* __restrict__ deg, int E) {
    int e = blockIdx.x * blockDim.x + threadIdx.x;
    if (e < E) atomicAdd(&deg[dst[e]], 1);
}

__global__ void scan_part1(const int* __restrict__ deg, int* __restrict__ bsum, int n) {
    __shared__ int p[256];
    int t = threadIdx.x;
    int base = blockIdx.x * SCAN_CHUNK + t * 4;
    int s = 0;
#pragma unroll
    for (int i = 0; i < 4; ++i) {
        int idx = base + i;
        if (idx < n) s += deg[idx];
    }
    p[t] = s;
    __syncthreads();
    for (int st = 128; st > 0; st >>= 1) {
        if (t < st) p[t] += p[t + st];
        __syncthreads();
    }
    if (t == 0) bsum[blockIdx.x] = p[0];
}

__global__ void scan_part2(const int* __restrict__ deg, const int* __restrict__ bsum,
                           int* __restrict__ off, int* __restrict__ cursor, int n, int nb) {
    __shared__ int p[256];
    __shared__ int sboff;
    int t = threadIdx.x;
    int b = blockIdx.x;

    int s = 0;
    for (int i = t; i < b; i += 256) s += bsum[i];
    p[t] = s;
    __syncthreads();
    for (int st = 128; st > 0; st >>= 1) {
        if (t < st) p[t] += p[t + st];
        __syncthreads();
    }
    if (t == 0) sboff = p[0];
    __syncthreads();
    int boff = sboff;

    int base = b * SCAN_CHUNK + t * 4;
    int d[4];
    int s4 = 0;
#pragma unroll
    for (int i = 0; i < 4; ++i) {
        int idx = base + i;
        d[i] = (idx < n) ? deg[idx] : 0;
        s4 += d[i];
    }
    __syncthreads();
    p[t] = s4;
    __syncthreads();
    for (int st = 1; st < 256; st <<= 1) {
        int v = (t >= st) ? p[t - st] : 0;
        __syncthreads();
        p[t] += v;
        __syncthreads();
    }
    int excl = boff + ((t == 0) ? 0 : p[t - 1]);
#pragma unroll
    for (int i = 0; i < 4; ++i) {
        int idx = base + i;
        if (idx < n) {
            off[idx] = excl;
            cursor[idx] = excl;
            excl += d[i];
        }
    }
    if (b == nb - 1 && t == 255) off[n] = boff + p[255];
}

__global__ void sort_kernel(const int* __restrict__ src, const int* __restrict__ dst,
                            int* __restrict__ cursor, int* __restrict__ ssrc, int E) {
    int e = blockIdx.x * blockDim.x + threadIdx.x;
    if (e < E) {
        int pos = atomicAdd(&cursor[dst[e]], 1);
        ssrc[pos] = src[e];
    }
}

// ---- fp32 -> bf16 converters ----

__global__ void cvt_x_kernel(const float* __restrict__ in, ushort* __restrict__ out, int n8) {
    int i = blockIdx.x * blockDim.x + threadIdx.x;
    if (i >= n8) return;
    const float4* p = (const float4*)in + (size_t)i * 2;
    float4 a = p[0], b = p[1];
    uint4 o;
    o.x = (uint)f2b(a.x) | ((uint)f2b(a.y) << 16);
    o.y = (uint)f2b(a.z) | ((uint)f2b(a.w) << 16);
    o.z = (uint)f2b(b.x) | ((uint)f2b(b.y) << 16);
    o.w = (uint)f2b(b.z) | ((uint)f2b(b.w) << 16);
    ((uint4*)out)[i] = o;
}

__global__ void cvt_weights_kernel(const float* __restrict__ a, const float* __restrict__ b,
                                   const float* __restrict__ c, const float* __restrict__ d,
                                   const float* __restrict__ e, ushort* __restrict__ out) {
    int i = blockIdx.x * blockDim.x + threadIdx.x;  // 0..81919
    const float* srcs[5] = {a, b, c, d, e};
    int seg = i >> 14;
    int off = i & 16383;
    out[i] = f2b(srcs[seg][off]);
}

// ---- mean-aggregate over sorted edge segments (bf16 in/out, fp32 accum) ----
__global__ void aggregate_bf16(const ushort* __restrict__ x, const int* __restrict__ ssrc,
                               const int* __restrict__ off, ushort* __restrict__ agg, int n) {
    int tid = blockIdx.x * blockDim.x + threadIdx.x;
    int node = tid >> 5;
    if (node >= n) return;
    int c = (tid & 31) << 2;
    int s0 = off[node], s1 = off[node + 1];
    float4 acc = {0.f, 0.f, 0.f, 0.f};
    int e = s0;
    for (; e + 1 < s1; e += 2) {
        int sa = ssrc[e], sb = ssrc[e + 1];
        uint2 va = *(const uint2*)(x + (size_t)sa * HF + c);
        uint2 vb = *(const uint2*)(x + (size_t)sb * HF + c);
        float4 fa = unpk(va), fb = unpk(vb);
        acc.x += fa.x + fb.x; acc.y += fa.y + fb.y;
        acc.z += fa.z + fb.z; acc.w += fa.w + fb.w;
    }
    if (e < s1) {
        uint2 va = *(const uint2*)(x + (size_t)ssrc[e] * HF + c);
        float4 fa = unpk(va);
        acc.x += fa.x; acc.y += fa.y; acc.z += fa.z; acc.w += fa.w;
    }
    float invd = 1.0f / fmaxf((float)(s1 - s0), 1.0f);
    uint2 o;
    o.x = (uint)f2b(acc.x * invd) | ((uint)f2b(acc.y * invd) << 16);
    o.y = (uint)f2b(acc.z * invd) | ((uint)f2b(acc.w * invd) << 16);
    *(uint2*)(agg + (size_t)node * HF + c) = o;
}

// ---- MFMA linear: out = relu(bias + A1@W1^T (+ A2@W2^T)), bf16 in/out, fp32 accum ----
// 64 rows/block, 4 waves; wave w owns cols [w*32, w*32+32) as two 16-col MFMA tiles.
// B frags in registers for whole block; A frags loaded direct from global (L1 shares
// across the 4 waves). No LDS, no barriers. Requires n % 16 == 0 tiles (100000%16==0).
template<bool DUAL>
__global__ __launch_bounds__(256)
void mfma_linear(const ushort* __restrict__ A1, const ushort* __restrict__ A2,
                 const ushort* __restrict__ W1, const ushort* __restrict__ W2,
                 const float* __restrict__ bias, ushort* __restrict__ out, int n) {
    int wave = threadIdx.x >> 6;
    int lane = threadIdx.x & 63;
    int m = lane & 15, quad = lane >> 4;
    int row0b = blockIdx.x * 64;

    bf16x8 b1[2][4], b2[2][4];
#pragma unroll
    for (int ct = 0; ct < 2; ++ct) {
        int col = wave * 32 + ct * 16 + m;
#pragma unroll
        for (int ks = 0; ks < 4; ++ks) {
            b1[ct][ks] = *(const bf16x8*)(W1 + (size_t)col * HF + ks * 32 + quad * 8);
            if (DUAL) b2[ct][ks] = *(const bf16x8*)(W2 + (size_t)col * HF + ks * 32 + quad * 8);
        }
    }
    float bia0 = bias[wave * 32 + m];
    float bia1 = bias[wave * 32 + 16 + m];

#pragma unroll
    for (int rt = 0; rt < 4; ++rt) {
        int row0 = row0b + rt * 16;
        if (row0 >= n) break;
        f32x4 acc0 = {0.f, 0.f, 0.f, 0.f};
        f32x4 acc1 = {0.f, 0.f, 0.f, 0.f};
        const ushort* arow = A1 + (size_t)(row0 + m) * HF + quad * 8;
#pragma unroll
        for (int ks = 0; ks < 4; ++ks) {
            bf16x8 a = *(const bf16x8*)(arow + ks * 32);
            acc0 = __builtin_amdgcn_mfma_f32_16x16x32_bf16(a, b1[0][ks], acc0, 0, 0, 0);
            acc1 = __builtin_amdgcn_mfma_f32_16x16x32_bf16(a, b1[1][ks], acc1, 0, 0, 0);
        }
        if (DUAL) {
            const ushort* arow2 = A2 + (size_t)(row0 + m) * HF + quad * 8;
#pragma unroll
            for (int ks = 0; ks < 4; ++ks) {
                bf16x8 a = *(const bf16x8*)(arow2 + ks * 32);
                acc0 = __builtin_amdgcn_mfma_f32_16x16x32_bf16(a, b2[0][ks], acc0, 0, 0, 0);
                acc1 = __builtin_amdgcn_mfma_f32_16x16x32_bf16(a, b2[1][ks], acc1, 0, 0, 0);
            }
        }
        // C/D layout: col = lane&15, row = quad*4 + reg
#pragma unroll
        for (int i = 0; i < 4; ++i) {
            size_t r = (size_t)(row0 + quad * 4 + i);
            out[r * HF + wave * 32 + m]      = f2b(fmaxf(acc0[i] + bia0, 0.f));
            out[r * HF + wave * 32 + 16 + m] = f2b(fmaxf(acc1[i] + bia1, 0.f));
        }
    }
}

// out[i][j] = sigmoid(bm2[j] + sum_k A[i][k]*W[j][k]), j < 20. A is bf16.
__global__ void head_kernel(const ushort* __restrict__ A, const float* __restrict__ W,
                            const float* __restrict__ bias, float* __restrict__ out, int n) {
    const int ROWS = 8;
    __shared__ float sA[ROWS * 129];
    __shared__ float sW[NC * 129];
    int row0 = blockIdx.x * ROWS;

    for (int idx = threadIdx.x; idx < NC * HF; idx += blockDim.x) {
        int j = idx >> 7, k = idx & (HF - 1);
        sW[j * 129 + k] = W[idx];
    }
    for (int idx = threadIdx.x; idx < ROWS * HF; idx += blockDim.x) {
        int r = idx >> 7, k = idx & (HF - 1);
        int i = row0 + r;
        sA[r * 129 + k] = (i < n) ? b2f(A[(size_t)i * HF + k]) : 0.f;
    }
    __syncthreads();

    int t = threadIdx.x;
    if (t < ROWS * NC) {
        int r = t / NC, j = t - r * NC;
        int i = row0 + r;
        if (i < n) {
            float acc = bias[j];
#pragma unroll 8
            for (int k = 0; k < HF; ++k)
                acc = fmaf(sA[r * 129 + k], sW[j * 129 + k], acc);
            out[(size_t)i * NC + j] = 1.0f / (1.0f + expf(-acc));
        }
    }
}

extern "C" void kernel_launch(void* const* d_in, const int* in_sizes, int n_in,
                              void* d_out, int out_size, void* d_ws, size_t ws_size,
                              hipStream_t stream) {
    const float* x   = (const float*)d_in[0];
    const int*   ei  = (const int*)d_in[1];
    const float* W1l = (const float*)d_in[2];
    const float* b1  = (const float*)d_in[3];
    const float* W1r = (const float*)d_in[4];
    const float* W2l = (const float*)d_in[5];
    const float* b2  = (const float*)d_in[6];
    const float* W2r = (const float*)d_in[7];
    const float* Wm1 = (const float*)d_in[8];
    const float* bm1 = (const float*)d_in[9];
    const float* Wm2 = (const float*)d_in[10];
    const float* bm2 = (const float*)d_in[11];
    float* out = (float*)d_out;

    const int N = NODES, E = EDGES;
    const int* src = ei;
    const int* dst = ei + E;

    // workspace layout: ints first (counts all %4==0 so bf16 region stays 16B-aligned)
    int* deg    = (int*)d_ws;            // N
    int* off    = deg + N;               // N+8 (padded)
    int* cursor = off + N + 8;           // N
    int* bsum   = cursor + N;            // 128
    int* ssrc   = bsum + 128;            // E
    ushort* xb   = (ushort*)(ssrc + E);  // N*HF each below
    ushort* aggA = xb + (size_t)N * HF;
    ushort* h1   = aggA + (size_t)N * HF;
    ushort* h2   = h1 + (size_t)N * HF;
    ushort* wb   = h2 + (size_t)N * HF;  // 5*16384 bf16 weights
    ushort* wb1l = wb;
    ushort* wb1r = wb + 16384;
    ushort* wb2l = wb + 32768;
    ushort* wb2r = wb + 49152;
    ushort* wbm1 = wb + 65536;

    const int NB = (N + SCAN_CHUNK - 1) / SCAN_CHUNK;

    // ---- edge sort by dst ----
    hipMemsetAsync(deg, 0, (size_t)N * sizeof(int), stream);
    count_kernel<<<(E + 255) / 256, 256, 0, stream>>>(dst, deg, E);
    scan_part1<<<NB, 256, 0, stream>>>(deg, bsum, N);
    scan_part2<<<NB, 256, 0, stream>>>(deg, bsum, off, cursor, N, NB);
    sort_kernel<<<(E + 255) / 256, 256, 0, stream>>>(src, dst, cursor, ssrc, E);

    // ---- bf16 conversion ----
    const int n8 = N * HF / 8;
    cvt_x_kernel<<<(n8 + 255) / 256, 256, 0, stream>>>(x, xb, n8);
    cvt_weights_kernel<<<320, 256, 0, stream>>>(W1l, W1r, W2l, W2r, Wm1, wb);

    const int aggBlocks = (N * 32 + 255) / 256;
    const int linBlocks = (N + 63) / 64;

    // ---- layer 1 ----
    aggregate_bf16<<<aggBlocks, 256, 0, stream>>>(xb, ssrc, off, aggA, N);
    mfma_linear<true><<<linBlocks, 256, 0, stream>>>(aggA, xb, wb1l, wb1r, b1, h1, N);

    // ---- layer 2 (agg output reuses xb) ----
    aggregate_bf16<<<aggBlocks, 256, 0, stream>>>(h1, ssrc, off, xb, N);
    mfma_linear<true><<<linBlocks, 256, 0, stream>>>(xb, h1, wb2l, wb2r, b2, h2, N);

    // ---- MLP hidden (out reuses aggA) ----
    mfma_linear<false><<<linBlocks, 256, 0, stream>>>(h2, nullptr, wbm1, nullptr, bm1, aggA, N);

    // ---- head + sigmoid ----
    head_kernel<<<(N + 7) / 8, 256, 0, stream>>>(aggA, Wm2, bm2, out, N);
}

// Round 5
// 500.359 us; speedup vs baseline: 12.1205x; 1.2629x over previous
//
#include <hip/hip_runtime.h>
#include <math.h>

#define NODES 100000
#define EDGES 1600000
#define HF 128
#define NC 20
#define BSHIFT 9
#define BK 512                          // nodes per bucket
#define NBK ((NODES + BK - 1) / BK)     // 196 buckets
#define EPB 8192                        // edges per partition block
#define NPB ((EDGES + EPB - 1) / EPB)   // 196 blocks

typedef __attribute__((ext_vector_type(8))) short bf16x8;
typedef __attribute__((ext_vector_type(4))) float f32x4;

__device__ __forceinline__ ushort f2b(float f) {
    uint u = __float_as_uint(f);
    uint r = (u + 0x7FFFu + ((u >> 16) & 1u)) >> 16;
    return (ushort)r;
}
__device__ __forceinline__ float b2f(ushort h) { return __uint_as_float(((uint)h) << 16); }
__device__ __forceinline__ float4 unpk(uint2 v) {
    float4 r;
    r.x = __uint_as_float(v.x << 16);
    r.y = __uint_as_float(v.x & 0xFFFF0000u);
    r.z = __uint_as_float(v.y << 16);
    r.w = __uint_as_float(v.y & 0xFFFF0000u);
    return r;
}

// ---- bucketed counting sort of edges by dst ----

// pass A: bucket totals via per-block LDS histogram
__global__ void bucket_hist(const int* __restrict__ dst, int* __restrict__ btot, int E) {
    __shared__ int h[NBK];
    for (int i = threadIdx.x; i < NBK; i += 256) h[i] = 0;
    __syncthreads();
    int base = blockIdx.x * EPB;
    for (int i = threadIdx.x; i < EPB; i += 256) {
        int e = base + i;
        if (e < E) atomicAdd(&h[dst[e] >> BSHIFT], 1);
    }
    __syncthreads();
    for (int i = threadIdx.x; i < NBK; i += 256)
        if (h[i]) atomicAdd(&btot[i], h[i]);
}

// scan of 196 bucket totals -> boff[0..NBK], bcur
__global__ void bucket_scan(const int* __restrict__ btot, int* __restrict__ boff,
                            int* __restrict__ bcur) {
    __shared__ int p[256];
    int t = threadIdx.x;
    p[t] = (t < NBK) ? btot[t] : 0;
    __syncthreads();
    for (int st = 1; st < 256; st <<= 1) {
        int u = (t >= st) ? p[t - st] : 0;
        __syncthreads();
        p[t] += u;
        __syncthreads();
    }
    int excl = (t == 0) ? 0 : p[t - 1];
    if (t < NBK) { boff[t] = excl; bcur[t] = excl; }
    if (t == NBK - 1) boff[NBK] = p[t];
}

// pass B: partition (src,dst) pairs into bucket-contiguous ebuf, block-ranked writes
__global__ void partition_kernel(const int* __restrict__ src, const int* __restrict__ dst,
                                 int* __restrict__ bcur, uint2* __restrict__ ebuf, int E) {
    __shared__ int h[NBK];
    __shared__ int basea[NBK];
    for (int i = threadIdx.x; i < NBK; i += 256) h[i] = 0;
    __syncthreads();
    int base = blockIdx.x * EPB;
    for (int i = threadIdx.x; i < EPB; i += 256) {
        int e = base + i;
        if (e < E) atomicAdd(&h[dst[e] >> BSHIFT], 1);
    }
    __syncthreads();
    for (int i = threadIdx.x; i < NBK; i += 256) {
        int c = h[i];
        basea[i] = c ? atomicAdd(&bcur[i], c) : 0;
    }
    __syncthreads();
    for (int i = threadIdx.x; i < NBK; i += 256) h[i] = 0;
    __syncthreads();
    for (int i = threadIdx.x; i < EPB; i += 256) {
        int e = base + i;
        if (e < E) {
            int d = dst[e];
            int b = d >> BSHIFT;
            int pos = basea[b] + atomicAdd(&h[b], 1);
            ebuf[pos] = make_uint2((uint)src[e], (uint)d);
        }
    }
}

// pass C: one block per bucket — local degree hist + scan -> off; scatter src -> ssrc.
// Scatter region (~32 KB) is owned by one block -> lines assemble in local L2.
__global__ void bucket_sort(const uint2* __restrict__ ebuf, const int* __restrict__ boff,
                            int* __restrict__ off, int* __restrict__ ssrc, int n) {
    __shared__ int deg[BK];
    __shared__ int lcur[BK];
    __shared__ int ps[BK];
    int b = blockIdx.x;
    int t = threadIdx.x;  // 0..511
    int e0 = boff[b], e1 = boff[b + 1];
    int nbase = b << BSHIFT;

    deg[t] = 0;
    __syncthreads();
    for (int e = e0 + t; e < e1; e += BK)
        atomicAdd(&deg[ebuf[e].y & (BK - 1)], 1);
    __syncthreads();
    // inclusive scan of deg -> ps
    ps[t] = deg[t];
    __syncthreads();
    for (int st = 1; st < BK; st <<= 1) {
        int u = (t >= st) ? ps[t - st] : 0;
        __syncthreads();
        ps[t] += u;
        __syncthreads();
    }
    int start = e0 + ((t == 0) ? 0 : ps[t - 1]);
    lcur[t] = start;
    int node = nbase + t;
    if (node < n) off[node] = start;
    __syncthreads();
    for (int e = e0 + t; e < e1; e += BK) {
        uint2 ed = ebuf[e];
        int pos = atomicAdd(&lcur[ed.y & (BK - 1)], 1);
        ssrc[pos] = (int)ed.x;
    }
    if (b == 0 && t == 0) off[n] = EDGES;
}

// ---- fp32 -> bf16 converters ----

__global__ void cvt_x_kernel(const float* __restrict__ in, ushort* __restrict__ out, int n8) {
    int i = blockIdx.x * blockDim.x + threadIdx.x;
    if (i >= n8) return;
    const float4* p = (const float4*)in + (size_t)i * 2;
    float4 a = p[0], b = p[1];
    uint4 o;
    o.x = (uint)f2b(a.x) | ((uint)f2b(a.y) << 16);
    o.y = (uint)f2b(a.z) | ((uint)f2b(a.w) << 16);
    o.z = (uint)f2b(b.x) | ((uint)f2b(b.y) << 16);
    o.w = (uint)f2b(b.z) | ((uint)f2b(b.w) << 16);
    ((uint4*)out)[i] = o;
}

__global__ void cvt_weights_kernel(const float* __restrict__ a, const float* __restrict__ b,
                                   const float* __restrict__ c, const float* __restrict__ d,
                                   const float* __restrict__ e, ushort* __restrict__ out) {
    int i = blockIdx.x * blockDim.x + threadIdx.x;  // 0..81919
    const float* srcs[5] = {a, b, c, d, e};
    int seg = i >> 14;
    int off = i & 16383;
    out[i] = f2b(srcs[seg][off]);
}

// ---- mean-aggregate over sorted edge segments (bf16 in/out, fp32 accum) ----
__global__ void aggregate_bf16(const ushort* __restrict__ x, const int* __restrict__ ssrc,
                               const int* __restrict__ off, ushort* __restrict__ agg, int n) {
    int tid = blockIdx.x * blockDim.x + threadIdx.x;
    int node = tid >> 5;
    if (node >= n) return;
    int c = (tid & 31) << 2;
    int s0 = off[node], s1 = off[node + 1];
    float4 acc = {0.f, 0.f, 0.f, 0.f};
    int e = s0;
    for (; e + 1 < s1; e += 2) {
        int sa = ssrc[e], sb = ssrc[e + 1];
        uint2 va = *(const uint2*)(x + (size_t)sa * HF + c);
        uint2 vb = *(const uint2*)(x + (size_t)sb * HF + c);
        float4 fa = unpk(va), fb = unpk(vb);
        acc.x += fa.x + fb.x; acc.y += fa.y + fb.y;
        acc.z += fa.z + fb.z; acc.w += fa.w + fb.w;
    }
    if (e < s1) {
        uint2 va = *(const uint2*)(x + (size_t)ssrc[e] * HF + c);
        float4 fa = unpk(va);
        acc.x += fa.x; acc.y += fa.y; acc.z += fa.z; acc.w += fa.w;
    }
    float invd = 1.0f / fmaxf((float)(s1 - s0), 1.0f);
    uint2 o;
    o.x = (uint)f2b(acc.x * invd) | ((uint)f2b(acc.y * invd) << 16);
    o.y = (uint)f2b(acc.z * invd) | ((uint)f2b(acc.w * invd) << 16);
    *(uint2*)(agg + (size_t)node * HF + c) = o;
}

// ---- MFMA linear: out = relu(bias + A1@W1^T (+ A2@W2^T)), bf16 in/out, fp32 accum ----
template<bool DUAL>
__global__ __launch_bounds__(256)
void mfma_linear(const ushort* __restrict__ A1, const ushort* __restrict__ A2,
                 const ushort* __restrict__ W1, const ushort* __restrict__ W2,
                 const float* __restrict__ bias, ushort* __restrict__ out, int n) {
    int wave = threadIdx.x >> 6;
    int lane = threadIdx.x & 63;
    int m = lane & 15, quad = lane >> 4;
    int row0b = blockIdx.x * 64;

    bf16x8 b1[2][4], b2[2][4];
#pragma unroll
    for (int ct = 0; ct < 2; ++ct) {
        int col = wave * 32 + ct * 16 + m;
#pragma unroll
        for (int ks = 0; ks < 4; ++ks) {
            b1[ct][ks] = *(const bf16x8*)(W1 + (size_t)col * HF + ks * 32 + quad * 8);
            if (DUAL) b2[ct][ks] = *(const bf16x8*)(W2 + (size_t)col * HF + ks * 32 + quad * 8);
        }
    }
    float bia0 = bias[wave * 32 + m];
    float bia1 = bias[wave * 32 + 16 + m];

#pragma unroll
    for (int rt = 0; rt < 4; ++rt) {
        int row0 = row0b + rt * 16;
        if (row0 >= n) break;
        f32x4 acc0 = {0.f, 0.f, 0.f, 0.f};
        f32x4 acc1 = {0.f, 0.f, 0.f, 0.f};
        const ushort* arow = A1 + (size_t)(row0 + m) * HF + quad * 8;
#pragma unroll
        for (int ks = 0; ks < 4; ++ks) {
            bf16x8 a = *(const bf16x8*)(arow + ks * 32);
            acc0 = __builtin_amdgcn_mfma_f32_16x16x32_bf16(a, b1[0][ks], acc0, 0, 0, 0);
            acc1 = __builtin_amdgcn_mfma_f32_16x16x32_bf16(a, b1[1][ks], acc1, 0, 0, 0);
        }
        if (DUAL) {
            const ushort* arow2 = A2 + (size_t)(row0 + m) * HF + quad * 8;
#pragma unroll
            for (int ks = 0; ks < 4; ++ks) {
                bf16x8 a = *(const bf16x8*)(arow2 + ks * 32);
                acc0 = __builtin_amdgcn_mfma_f32_16x16x32_bf16(a, b2[0][ks], acc0, 0, 0, 0);
                acc1 = __builtin_amdgcn_mfma_f32_16x16x32_bf16(a, b2[1][ks], acc1, 0, 0, 0);
            }
        }
        // C/D layout: col = lane&15, row = quad*4 + reg
#pragma unroll
        for (int i = 0; i < 4; ++i) {
            size_t r = (size_t)(row0 + quad * 4 + i);
            out[r * HF + wave * 32 + m]      = f2b(fmaxf(acc0[i] + bia0, 0.f));
            out[r * HF + wave * 32 + 16 + m] = f2b(fmaxf(acc1[i] + bia1, 0.f));
        }
    }
}

// out[i][j] = sigmoid(bm2[j] + sum_k A[i][k]*W[j][k]), j < 20. A is bf16.
__global__ void head_kernel(const ushort* __restrict__ A, const float* __restrict__ W,
                            const float* __restrict__ bias, float* __restrict__ out, int n) {
    const int ROWS = 8;
    __shared__ float sA[ROWS * 129];
    __shared__ float sW[NC * 129];
    int row0 = blockIdx.x * ROWS;

    for (int idx = threadIdx.x; idx < NC * HF; idx += blockDim.x) {
        int j = idx >> 7, k = idx & (HF - 1);
        sW[j * 129 + k] = W[idx];
    }
    for (int idx = threadIdx.x; idx < ROWS * HF; idx += blockDim.x) {
        int r = idx >> 7, k = idx & (HF - 1);
        int i = row0 + r;
        sA[r * 129 + k] = (i < n) ? b2f(A[(size_t)i * HF + k]) : 0.f;
    }
    __syncthreads();

    int t = threadIdx.x;
    if (t < ROWS * NC) {
        int r = t / NC, j = t - r * NC;
        int i = row0 + r;
        if (i < n) {
            float acc = bias[j];
#pragma unroll 8
            for (int k = 0; k < HF; ++k)
                acc = fmaf(sA[r * 129 + k], sW[j * 129 + k], acc);
            out[(size_t)i * NC + j] = 1.0f / (1.0f + expf(-acc));
        }
    }
}

extern "C" void kernel_launch(void* const* d_in, const int* in_sizes, int n_in,
                              void* d_out, int out_size, void* d_ws, size_t ws_size,
                              hipStream_t stream) {
    const float* x   = (const float*)d_in[0];
    const int*   ei  = (const int*)d_in[1];
    const float* W1l = (const float*)d_in[2];
    const float* b1  = (const float*)d_in[3];
    const float* W1r = (const float*)d_in[4];
    const float* W2l = (const float*)d_in[5];
    const float* b2  = (const float*)d_in[6];
    const float* W2r = (const float*)d_in[7];
    const float* Wm1 = (const float*)d_in[8];
    const float* bm1 = (const float*)d_in[9];
    const float* Wm2 = (const float*)d_in[10];
    const float* bm2 = (const float*)d_in[11];
    float* out = (float*)d_out;

    const int N = NODES, E = EDGES;
    const int* src = ei;
    const int* dst = ei + E;

    // workspace layout (16B-aligned sections)
    int* boff   = (int*)d_ws;            // 256 (NBK+1 used)
    int* btot   = boff + 256;            // 256
    int* bcur   = btot + 256;            // 256
    int* off    = bcur + 256;            // N+8
    int* ssrc   = off + N + 8;           // E
    ushort* xb   = (ushort*)(ssrc + E);  // N*HF each below
    ushort* aggA = xb + (size_t)N * HF;
    ushort* h1   = aggA + (size_t)N * HF;
    ushort* h2   = h1 + (size_t)N * HF;
    uint2* ebuf  = (uint2*)h2;           // aliases h2 (dead until layer-2 linear)
    ushort* wb   = h2 + (size_t)N * HF;  // 5*16384 bf16 weights
    ushort* wb1l = wb;
    ushort* wb1r = wb + 16384;
    ushort* wb2l = wb + 32768;
    ushort* wb2r = wb + 49152;
    ushort* wbm1 = wb + 65536;

    // ---- bucketed sort of edges by dst ----
    hipMemsetAsync(btot, 0, 256 * sizeof(int), stream);
    bucket_hist<<<NPB, 256, 0, stream>>>(dst, btot, E);
    bucket_scan<<<1, 256, 0, stream>>>(btot, boff, bcur);
    partition_kernel<<<NPB, 256, 0, stream>>>(src, dst, bcur, ebuf, E);
    bucket_sort<<<NBK, BK, 0, stream>>>(ebuf, boff, off, ssrc, N);

    // ---- bf16 conversion ----
    const int n8 = N * HF / 8;
    cvt_x_kernel<<<(n8 + 255) / 256, 256, 0, stream>>>(x, xb, n8);
    cvt_weights_kernel<<<320, 256, 0, stream>>>(W1l, W1r, W2l, W2r, Wm1, wb);

    const int aggBlocks = (N * 32 + 255) / 256;
    const int linBlocks = (N + 63) / 64;

    // ---- layer 1 ----
    aggregate_bf16<<<aggBlocks, 256, 0, stream>>>(xb, ssrc, off, aggA, N);
    mfma_linear<true><<<linBlocks, 256, 0, stream>>>(aggA, xb, wb1l, wb1r, b1, h1, N);

    // ---- layer 2 (agg output reuses xb; ebuf/h2 region now free for h2) ----
    aggregate_bf16<<<aggBlocks, 256, 0, stream>>>(h1, ssrc, off, xb, N);
    mfma_linear<true><<<linBlocks, 256, 0, stream>>>(xb, h1, wb2l, wb2r, b2, h2, N);

    // ---- MLP hidden (out reuses aggA) ----
    mfma_linear<false><<<linBlocks, 256, 0, stream>>>(h2, nullptr, wbm1, nullptr, bm1, aggA, N);

    // ---- head + sigmoid ----
    head_kernel<<<(N + 7) / 8, 256, 0, stream>>>(aggA, Wm2, bm2, out, N);
}